// Round 1
// baseline (543.197 us; speedup 1.0000x reference)
//
#include <hip/hip_runtime.h>
#include <stdint.h>

// Problem constants (fixed by the reference)
#define E_N   500000
#define G_N   25000
#define HIDN  128
#define KIN   272
#define NKSTEP 9        // K padded 272 -> 288 = 9 * 32
#define WB_ELEMS 36864  // 9*8*64*8 bf16 fragment-ordered W1
#define ROWS   256      // rows per block
#define ABUF_F 8192     // floats per A stage buffer: 256 rows * 32 f32 = 32 KB

typedef short bfrag_t __attribute__((ext_vector_type(8)));  // 8 bf16 = 4 VGPRs
typedef float accf4  __attribute__((ext_vector_type(4)));   // 4 f32 acc

// round-to-nearest (ties away) f32->bf16 pair pack: 3 VALU ops
__device__ __forceinline__ uint32_t pack2_bf16(float a, float b) {
    uint32_t ua = __builtin_bit_cast(uint32_t, a) + 0x8000u;
    uint32_t ub = __builtin_bit_cast(uint32_t, b) + 0x8000u;
    // v_perm_b32: S0=ub, S1=ua; result = hi16(ua) | hi16(ub)<<16
    return __builtin_amdgcn_perm(ub, ua, 0x07060302u);
}

// async global->LDS, 16B per lane; LDS dest is linear (wave base + lane*16)
__device__ __forceinline__ void gl2lds16(const void* g, void* l) {
    __builtin_amdgcn_global_load_lds(
        (const __attribute__((address_space(1))) void*)g,
        (__attribute__((address_space(3))) void*)l, 16, 0, 0);
}

// ---------------- prep: zero seg_sum; build Wb in MFMA B-fragment order (RNE).
// Wb[((s*8+b)*64 + lane)*8 + j] = bf16( W1[k][n] ), k = s*32 + (lane>>4)*8 + j,
// n = b*16 + (lane&15); zero-pad k >= 272.
__global__ void prep_kernel(const float* __restrict__ W1, float* __restrict__ seg_sum,
                            ushort* __restrict__ Wb) {
    int t = blockIdx.x * 256 + threadIdx.x;   // grid = 144*256 = 36864 exactly
    if (t < G_N) seg_sum[t] = 0.0f;
    int j    = t & 7;
    int lane = (t >> 3) & 63;
    int sb   = t >> 9;          // s*8 + b
    int b    = sb & 7;
    int s    = sb >> 3;
    int k    = s * 32 + (lane >> 4) * 8 + j;
    int n    = b * 16 + (lane & 15);
    ushort v = 0;
    if (k < KIN) {
        uint32_t u = __builtin_bit_cast(uint32_t, W1[k * HIDN + n]);
        u += 0x7FFFu + ((u >> 16) & 1u);
        v = (ushort)(u >> 16);
    }
    Wb[t] = v;
}

// ---------------- main: fused MLP (GEMM1 + relu + GEMM2) + exp + segment-sum
// Block = 512 threads (8 waves), 256 rows/block, 1 block/CU (136 KB LDS).
// A is staged global->LDS via async global_load_lds, double-buffered, with a
// counted vmcnt(4) + raw s_barrier pipeline (never __syncthreads in the loop,
// which would drain the queue). LDS A layout is XOR-swizzled (byte ^= (row&7)<<4)
// achieved by pre-swizzling the per-lane GLOBAL source address (LDS dest must
// stay linear for global_load_lds); the fragment ds_read applies the same XOR,
// giving a free 2-way bank aliasing instead of 16-way conflicts.
__launch_bounds__(512, 2)
__global__ void mlp_kernel(const float* __restrict__ src, const float* __restrict__ dst,
                           const float* __restrict__ attr, const ushort* __restrict__ Wb,
                           const float* __restrict__ b1, const float* __restrict__ W2,
                           const float* __restrict__ b2, const int* __restrict__ gidx,
                           float* __restrict__ logits_out, float* __restrict__ ex_out,
                           float* __restrict__ seg_sum) {
    __shared__ __align__(16) float  Alds[2][ABUF_F];   // 2 x 32768 B
    __shared__ __align__(16) ushort Blds[WB_ELEMS];    // 73728 B

    const int tid  = threadIdx.x;
    const int lane = tid & 63;
    const int wave = tid >> 6;
    const int m    = lane & 15;   // row-within-tile (A), col-within-tile (B/C)
    const int q    = lane >> 4;   // k-quad (A/B), row-quad (C)
    const int rowbase = blockIdx.x * ROWS;

    // ---- B stage: 9 x 16B chunks/thread, async (fragment order is lane-linear)
    #pragma unroll
    for (int i = 0; i < 9; ++i) {
        const int c = i * 512 + tid;
        gl2lds16((const char*)Wb + (size_t)c * 16, (char*)Blds + c * 16);
    }

    // ---- per-thread A-staging constants (chunk c = i*512+tid; 16B chunks)
    // LDS byte L = c*16 (linear); r_loc = c>>3; cb_lin = (c&7)*16.
    // Global source col-bytes = cb_lin ^ ((r_loc&7)<<4)  (pre-swizzle).
    int rowi[4], gba[4], loff[4];
    #pragma unroll
    for (int i = 0; i < 4; ++i) {
        const int c  = i * 512 + tid;
        const int rl = c >> 3;
        gba[i] = ((c & 7) * 16) ^ ((rl & 7) << 4);
        const int row = rowbase + rl;
        rowi[i] = row < E_N ? row : (E_N - 1);   // branch-free clamp
        loff[i] = c * 16;
    }

    // ---- issue stage(0) (src, k-cols 0..31)
    #pragma unroll
    for (int i = 0; i < 4; ++i)
        gl2lds16((const char*)src + (size_t)rowi[i] * 512 + gba[i],
                 (char*)Alds[0] + loff[i]);

    accf4 acc[2][8];
    #pragma unroll
    for (int a = 0; a < 2; ++a)
        #pragma unroll
        for (int b = 0; b < 8; ++b)
            acc[a][b] = (accf4)(0.0f);

    // compute-side constants: two 16-row a-tiles per wave; same swizzle for both
    const int rl0 = wave * 32 + m;
    const int rl1 = rl0 + 16;
    const int swz = (rl0 & 7) << 4;           // (rl1&7)==(rl0&7)
    const int cb0 = (q * 32) ^ swz;           // swizzled byte cols of the 2 b128s
    const int cb1 = (q * 32 + 16) ^ swz;

    for (int s = 0; s < NKSTEP; ++s) {
        // issue stage(s+1) into the other buffer (prev barrier freed it),
        // then wait only for stage(s): counted vmcnt keeps s+1 in flight.
        if (s + 1 < NKSTEP) {
            const int sn = s + 1;
            char* abuf = (char*)Alds[sn & 1];
            if (sn < 8) {
                const char* bse = (const char*)(sn < 4 ? src : dst);
                const int co = (sn & 3) * 128;   // k-col byte offset within 512B row
                #pragma unroll
                for (int i = 0; i < 4; ++i)
                    gl2lds16(bse + (size_t)rowi[i] * 512 + co + gba[i], abuf + loff[i]);
            } else {
                // attr rows are 64B; cb>=64 chunks read duplicates (cb&63) —
                // they land in k>=272 fragment slots where B is zero-padded.
                #pragma unroll
                for (int i = 0; i < 4; ++i)
                    gl2lds16((const char*)attr + (size_t)rowi[i] * 64 + (gba[i] & 63),
                             abuf + loff[i]);
            }
            asm volatile("s_waitcnt vmcnt(4)" ::: "memory");
        } else {
            asm volatile("s_waitcnt vmcnt(0)" ::: "memory");
        }
        __builtin_amdgcn_s_barrier();   // stage(s) visible to all waves

        // A fragments from swizzled LDS, pack f32->bf16
        const char* rp0 = (const char*)Alds[s & 1] + rl0 * 128;
        const char* rp1 = (const char*)Alds[s & 1] + rl1 * 128;
        bfrag_t af[2];
        {
            float4 x0 = *(const float4*)(rp0 + cb0);
            float4 x1 = *(const float4*)(rp0 + cb1);
            uint4 u;
            u.x = pack2_bf16(x0.x, x0.y);
            u.y = pack2_bf16(x0.z, x0.w);
            u.z = pack2_bf16(x1.x, x1.y);
            u.w = pack2_bf16(x1.z, x1.w);
            af[0] = *(bfrag_t*)&u;
        }
        {
            float4 x0 = *(const float4*)(rp1 + cb0);
            float4 x1 = *(const float4*)(rp1 + cb1);
            uint4 u;
            u.x = pack2_bf16(x0.x, x0.y);
            u.y = pack2_bf16(x0.z, x0.w);
            u.z = pack2_bf16(x1.x, x1.y);
            u.w = pack2_bf16(x1.z, x1.w);
            af[1] = *(bfrag_t*)&u;
        }

        // B fragments from LDS + MFMA
        #pragma unroll
        for (int b = 0; b < 8; ++b) {
            bfrag_t bf = *(const bfrag_t*)&Blds[(size_t)((s * 8 + b) * 64 + lane) * 8];
            acc[0][b] = __builtin_amdgcn_mfma_f32_16x16x32_bf16(af[0], bf, acc[0][b], 0, 0, 0);
            acc[1][b] = __builtin_amdgcn_mfma_f32_16x16x32_bf16(af[1], bf, acc[1][b], 0, 0, 0);
        }
        __builtin_amdgcn_s_barrier();   // compute(s) done -> buf[s&1] reusable
    }

    // ---- epilogue: h = relu(acc + b1); logit = h . W2 + b2 (f32 throughout)
    float w2v[8], b1v[8];
    #pragma unroll
    for (int b = 0; b < 8; ++b) {
        w2v[b] = W2[b * 16 + m];
        b1v[b] = b1[b * 16 + m];
    }
    const float bias2 = b2[0];
    const int wrow = rowbase + wave * 32;

    #pragma unroll
    for (int a = 0; a < 2; ++a) {
        float p4[4] = {0.f, 0.f, 0.f, 0.f};
        #pragma unroll
        for (int b = 0; b < 8; ++b)
            #pragma unroll
            for (int rr = 0; rr < 4; ++rr) {
                float h = acc[a][b][rr] + b1v[b];
                h = h > 0.f ? h : 0.f;
                p4[rr] += h * w2v[b];
            }
        #pragma unroll
        for (int rr = 0; rr < 4; ++rr) {
            float v = p4[rr];
            v += __shfl_xor(v, 1);   // reduce across the 16 column-lanes
            v += __shfl_xor(v, 2);
            v += __shfl_xor(v, 4);
            v += __shfl_xor(v, 8);
            if (m == 0) {
                int grow = wrow + a * 16 + q * 4 + rr;
                if (grow < E_N) {
                    float logit = v + bias2;
                    logits_out[grow] = logit;
                    float ex = __expf(logit);   // no max-subtraction: |logit| < ~6
                    ex_out[grow] = ex;
                    atomicAdd(&seg_sum[gidx[grow]], ex);
                }
            }
        }
    }
}

// ---------------- normalize: weight = ex / seg_sum[g]
__global__ void norm_kernel(const float* __restrict__ ex, const float* __restrict__ seg_sum,
                            const int* __restrict__ gidx, float* __restrict__ wout) {
    int e = blockIdx.x * 256 + threadIdx.x;
    if (e < E_N) wout[e] = ex[e] / seg_sum[gidx[e]];
}

extern "C" void kernel_launch(void* const* d_in, const int* in_sizes, int n_in,
                              void* d_out, int out_size, void* d_ws, size_t ws_size,
                              hipStream_t stream) {
    const float* src  = (const float*)d_in[0];
    const float* dst  = (const float*)d_in[1];
    const float* attr = (const float*)d_in[2];
    const float* W1   = (const float*)d_in[3];
    const float* b1   = (const float*)d_in[4];
    const float* W2   = (const float*)d_in[5];
    const float* b2   = (const float*)d_in[6];
    const int*   gidx = (const int*)d_in[7];
    // d_in[8] = num_groups (constant 25000, baked in)

    float* weights_out = (float*)d_out;          // [E] (shape [E,1])
    float* logits_out  = (float*)d_out + E_N;    // [E]

    char* ws = (char*)d_ws;
    ushort* Wb  = (ushort*)ws;                          // 36864*2 = 73728 B
    float*  seg = (float*)(ws + 73728);                 // 25000*4 = 100000 B
    float*  ex  = (float*)(ws + 173728);                // 500000*4 = 2 MB

    prep_kernel<<<144, 256, 0, stream>>>(W1, seg, Wb);

    const int nblk = (E_N + ROWS - 1) / ROWS;   // 1954 (256 rows/block)
    mlp_kernel<<<nblk, 512, 0, stream>>>(src, dst, attr, Wb, b1, W2, b2, gidx,
                                         logits_out, ex, seg);
    norm_kernel<<<(E_N + 255) / 256, 256, 0, stream>>>(ex, seg, gidx, weights_out);
}